// Round 1
// baseline (620.187 us; speedup 1.0000x reference)
//
#include <hip/hip_runtime.h>
#include <hip/hip_fp16.h>
#include <cstdint>
#include <cstddef>

// ---------------------------------------------------------------------------
// VectorQuantizerEMA on MI355X.
// Sizes fixed by the reference: B=8,S=2048,D=256,K=4096 -> N=16384 tokens.
// Pipeline:
//   1) split z and codebook into fp16 (h1, h2*2^11) packed rows [row][512 halves]
//      (+ fp64 codebook row norms)
//   2) distance GEMM via 3x mfma_f32_16x16x32_f16 (h1h1 -> acc1, cross -> acc2),
//      fp64 epilogue argmin per token per 128-entry block -> candidate arrays
//   3) merge candidates per token; gather codebook row -> out; loss partials;
//      atomic scatter of n / dw
//   4) new_weight elementwise; new_count normalize + loss finalize
// ---------------------------------------------------------------------------

#define N_TOK 16384
#define DIM   256
#define K_CB  4096

typedef _Float16 h8    __attribute__((ext_vector_type(8)));
typedef float    f32x4 __attribute__((ext_vector_type(4)));

// ---- ws layout (bytes) ----
#define WS_ZPACK   0u            // N_TOK * 512 halves  = 16 MB
#define WS_CPACK   16777216u     // K_CB * 512 halves   = 4 MB
#define WS_CNORM   20971520u     // K_CB doubles        = 32 KB
#define WS_CANDV   21004288u     // N_TOK * 64 doubles  = 8 MB
#define WS_CANDI   29392896u     // N_TOK * 64 int      = 4 MB
#define WS_DW      33587200u     // K_CB * DIM float    = 4 MB
#define WS_NACC    37781504u     // K_CB float          = 16 KB
#define WS_LOSS    37797888u     // 2 floats (+pad)
#define WS_ZERO_BYTES (4194304u + 16384u + 16u)

__device__ __forceinline__ void gload_lds16(const void* g, void* l) {
  __builtin_amdgcn_global_load_lds(
      (const __attribute__((address_space(1))) uint32_t*)g,
      (__attribute__((address_space(3))) uint32_t*)l, 16, 0, 0);
}

// ---- 1a: split z into packed fp16 pair rows --------------------------------
__global__ void vq_split_z(const float* __restrict__ z, unsigned short* __restrict__ pack) {
  int tid = blockIdx.x * 256 + threadIdx.x;       // over N_TOK*64
  int row = tid >> 6, c4 = tid & 63;
  float4 v = reinterpret_cast<const float4*>(z)[tid];
  float x[4] = {v.x, v.y, v.z, v.w};
  union { _Float16 h[4]; ushort4 u; } a, b;
#pragma unroll
  for (int i = 0; i < 4; ++i) {
    _Float16 h1 = (_Float16)x[i];
    float lo = x[i] - (float)h1;
    a.h[i] = h1;
    b.h[i] = (_Float16)(lo * 2048.0f);   // scaled to avoid fp16 denormal loss
  }
  reinterpret_cast<ushort4*>(pack)[row * 128 + c4]      = a.u;
  reinterpret_cast<ushort4*>(pack)[row * 128 + 64 + c4] = b.u;
}

// ---- 1b: split codebook + fp64 row norms -----------------------------------
__global__ void vq_split_c(const float* __restrict__ cb, unsigned short* __restrict__ pack,
                           double* __restrict__ cnorm) {
  int w = threadIdx.x >> 6, l = threadIdx.x & 63;
  int row = blockIdx.x * 4 + w;
  float4 v = reinterpret_cast<const float4*>(cb)[row * 64 + l];
  float x[4] = {v.x, v.y, v.z, v.w};
  union { _Float16 h[4]; ushort4 u; } a, b;
  double ss = 0.0;
#pragma unroll
  for (int i = 0; i < 4; ++i) {
    _Float16 h1 = (_Float16)x[i];
    float lo = x[i] - (float)h1;
    a.h[i] = h1;
    b.h[i] = (_Float16)(lo * 2048.0f);
    ss += (double)x[i] * (double)x[i];
  }
  reinterpret_cast<ushort4*>(pack)[row * 128 + l]      = a.u;
  reinterpret_cast<ushort4*>(pack)[row * 128 + 64 + l] = b.u;
  for (int off = 1; off < 64; off <<= 1) ss += __shfl_xor(ss, off);
  if (l == 0) cnorm[row] = ss;
}

// ---- 2: distance GEMM + per-block argmin -----------------------------------
// Block: 256 thr = 4 waves (2x2). Tile 128 tokens x 128 entries, BK=32 halves.
// LDS row layout: [row][8 chunks of 16B], chunks 0-3 = h1 k0..31, 4-7 = h2s;
// stored chunk = logical_chunk ^ (row&7)  -> conflict-free ds_read_b128.
// global_load_lds writes linearly; the swizzle is applied on the global SOURCE.
__global__ __launch_bounds__(256, 2) void vq_gemm(
    const unsigned short* __restrict__ zpack, const unsigned short* __restrict__ cpack,
    const double* __restrict__ cnorm,
    double* __restrict__ cand_val, int* __restrict__ cand_idx) {
  __shared__ __align__(1024) unsigned char lds[32768];   // A 16KB | B 16KB

  // XCD-aware bijective swizzle: 4096 blocks, 8 XCDs, chunk of 512/XCD.
  // Within a chunk: 16 consecutive mb (fast) x 32 nb (slow) -> B-panel L2 reuse.
  const int bid = blockIdx.x;
  const int wg  = (bid & 7) * 512 + (bid >> 3);
  const int mb  = (wg >> 9) * 16 + (wg & 15);   // 0..127
  const int nb  = (wg >> 4) & 31;               // 0..31
  const int token0 = mb * 128, entry0 = nb * 128;

  const int tx = threadIdx.x;
  const int w  = tx >> 6, l = tx & 63;
  const int waveM = w >> 1, waveN = w & 1;

  // staging lane constants: each wave-load covers 8 rows x 8 chunks (1 KB)
  const int rlo = l >> 3;            // row within 8-row group
  const int ch  = l & 7;             // stored chunk this lane fills
  const int lc  = ch ^ rlo;          // logical chunk to fetch
  const int s_  = lc >> 2, c_ = lc & 3;
  const unsigned char* zb  = (const unsigned char*)zpack;
  const unsigned char* cbp = (const unsigned char*)cpack;
  const unsigned char* srcA[4]; const unsigned char* srcB[4];
  unsigned char* dstA[4]; unsigned char* dstB[4];
#pragma unroll
  for (int j = 0; j < 4; ++j) {
    size_t rA = (size_t)(token0 + w * 32 + j * 8 + rlo);
    size_t rB = (size_t)(entry0 + w * 32 + j * 8 + rlo);
    srcA[j] = zb  + rA * 1024 + s_ * 512 + c_ * 16;
    srcB[j] = cbp + rB * 1024 + s_ * 512 + c_ * 16;
    dstA[j] = &lds[0]     + (w * 32 + j * 8) * 128;
    dstB[j] = &lds[16384] + (w * 32 + j * 8) * 128;
  }

  f32x4 zero = {0.f, 0.f, 0.f, 0.f};
  f32x4 acc1[4][4], acc2[4][4];
#pragma unroll
  for (int m = 0; m < 4; ++m)
#pragma unroll
    for (int n = 0; n < 4; ++n) { acc1[m][n] = zero; acc2[m][n] = zero; }

  const int fr = l & 15, fk = l >> 4;

  for (int t = 0; t < 8; ++t) {
#pragma unroll
    for (int j = 0; j < 4; ++j) {
      gload_lds16(srcA[j] + t * 64, dstA[j]);
      gload_lds16(srcB[j] + t * 64, dstB[j]);
    }
    __syncthreads();

    h8 a1[4], a2[4], b1[4], b2[4];
#pragma unroll
    for (int m = 0; m < 4; ++m) {
      int r = waveM * 64 + m * 16 + fr;
      int st0 = (fk)     ^ (r & 7);
      int st1 = (4 + fk) ^ (r & 7);
      a1[m] = *(const h8*)&lds[r * 128 + st0 * 16];
      a2[m] = *(const h8*)&lds[r * 128 + st1 * 16];
    }
#pragma unroll
    for (int n = 0; n < 4; ++n) {
      int r = waveN * 64 + n * 16 + fr;
      int st0 = (fk)     ^ (r & 7);
      int st1 = (4 + fk) ^ (r & 7);
      b1[n] = *(const h8*)&lds[16384 + r * 128 + st0 * 16];
      b2[n] = *(const h8*)&lds[16384 + r * 128 + st1 * 16];
    }
#pragma unroll
    for (int m = 0; m < 4; ++m)
#pragma unroll
      for (int n = 0; n < 4; ++n) {
        acc1[m][n] = __builtin_amdgcn_mfma_f32_16x16x32_f16(a1[m], b1[n], acc1[m][n], 0, 0, 0);
        acc2[m][n] = __builtin_amdgcn_mfma_f32_16x16x32_f16(a1[m], b2[n], acc2[m][n], 0, 0, 0);
        acc2[m][n] = __builtin_amdgcn_mfma_f32_16x16x32_f16(a2[m], b1[n], acc2[m][n], 0, 0, 0);
      }
    __syncthreads();
  }

  // epilogue: d = |c|^2 - 2*(acc1 + acc2/2048) in fp64, per-token argmin
  double cn[4];
#pragma unroll
  for (int n = 0; n < 4; ++n) cn[n] = cnorm[entry0 + waveN * 64 + n * 16 + fr];

#pragma unroll
  for (int m = 0; m < 4; ++m) {
#pragma unroll
    for (int rI = 0; rI < 4; ++rI) {
      double bd = 1e300; int bi = 0x7fffffff;
#pragma unroll
      for (int n = 0; n < 4; ++n) {
        double s = (double)acc1[m][n][rI] + (double)acc2[m][n][rI] * (1.0 / 2048.0);
        double d = cn[n] - 2.0 * s;
        int e = entry0 + waveN * 64 + n * 16 + fr;
        if (d < bd || (d == bd && e < bi)) { bd = d; bi = e; }
      }
      for (int off = 1; off < 16; off <<= 1) {   // reduce across 16 fragment cols
        double od = __shfl_xor(bd, off);
        int    oi = __shfl_xor(bi, off);
        if (od < bd || (od == bd && oi < bi)) { bd = od; bi = oi; }
      }
      if (fr == 0) {
        int token = token0 + waveM * 64 + m * 16 + fk * 4 + rI;
        int slot  = nb * 2 + waveN;              // 64 slots per token
        cand_val[(size_t)token * 64 + slot] = bd;
        cand_idx[(size_t)token * 64 + slot] = bi;
      }
    }
  }
}

// ---- 3: merge candidates; out/indices/loss; scatter n/dw -------------------
__global__ void vq_merge_scatter(
    const double* __restrict__ cand_val, const int* __restrict__ cand_idx,
    const float* __restrict__ z, const float* __restrict__ mask,
    const float* __restrict__ codebook,
    float* __restrict__ out0, float* __restrict__ out_idx,
    float* __restrict__ dw, float* __restrict__ nacc, float* __restrict__ loss2) {
  int w = threadIdx.x >> 6, l = threadIdx.x & 63;
  int token = blockIdx.x * 4 + w;

  double bv = cand_val[(size_t)token * 64 + l];
  int    bi = cand_idx[(size_t)token * 64 + l];
  for (int off = 1; off < 64; off <<= 1) {
    double ov = __shfl_xor(bv, off);
    int    oi = __shfl_xor(bi, off);
    if (ov < bv || (ov == bv && oi < bi)) { bv = ov; bi = oi; }
  }

  float4 cv = reinterpret_cast<const float4*>(codebook)[(size_t)bi * 64 + l];
  reinterpret_cast<float4*>(out0)[(size_t)token * 64 + l] = cv;   // out == quantized
  float4 zv = reinterpret_cast<const float4*>(z)[(size_t)token * 64 + l];

  float dx = zv.x - cv.x, dy = zv.y - cv.y, dz = zv.z - cv.z, dww = zv.w - cv.w;
  float ssd = dx * dx + dy * dy + dz * dz + dww * dww;
  for (int off = 1; off < 64; off <<= 1) ssd += __shfl_xor(ssd, off);

  float mk = mask[token];
  if (l == 0) {
    out_idx[token] = (float)bi;
    atomicAdd(&loss2[0], mk * ssd * (1.0f / 256.0f));
    atomicAdd(&loss2[1], mk);
    atomicAdd(&nacc[bi], mk);
  }
  if (mk != 0.0f) {
    float* p = dw + (size_t)bi * 256 + l * 4;
    atomicAdd(p + 0, mk * zv.x);
    atomicAdd(p + 1, mk * zv.y);
    atomicAdd(p + 2, mk * zv.z);
    atomicAdd(p + 3, mk * zv.w);
  }
}

// ---- 4a: new_weight --------------------------------------------------------
__global__ void vq_finish_weight(const float* __restrict__ ew, const float* __restrict__ dw,
                                 float* __restrict__ nw) {
  int i = blockIdx.x * 256 + threadIdx.x;       // over K*D/4
  float4 e = reinterpret_cast<const float4*>(ew)[i];
  float4 d = reinterpret_cast<const float4*>(dw)[i];
  float4 o;
  o.x = 0.99f * e.x + 0.01f * d.x;
  o.y = 0.99f * e.y + 0.01f * d.y;
  o.z = 0.99f * e.z + 0.01f * d.z;
  o.w = 0.99f * e.w + 0.01f * d.w;
  reinterpret_cast<float4*>(nw)[i] = o;
}

// ---- 4b: new_count normalize + loss finalize -------------------------------
__global__ void vq_finish_count(const float* __restrict__ ec, const float* __restrict__ nacc,
                                const float* __restrict__ loss2,
                                float* __restrict__ out_count, float* __restrict__ out_loss) {
  __shared__ float nc_s[K_CB];
  __shared__ float red[256];
  int tid = threadIdx.x;
  float part = 0.f;
  for (int i = tid; i < K_CB; i += 256) {
    float nc = 0.99f * ec[i] + 0.01f * nacc[i];
    nc_s[i] = nc; part += nc;
  }
  red[tid] = part; __syncthreads();
  for (int s = 128; s > 0; s >>= 1) { if (tid < s) red[tid] += red[tid + s]; __syncthreads(); }
  float total = red[0];
  float scale = total / (total + (float)K_CB * 1e-5f);
  for (int i = tid; i < K_CB; i += 256) out_count[i] = (nc_s[i] + 1e-5f) * scale;
  if (tid == 0) out_loss[0] = 2.5f * loss2[0] / loss2[1];   // 10 * 0.25 * num/den
}

extern "C" void kernel_launch(void* const* d_in, const int* in_sizes, int n_in,
                              void* d_out, int out_size, void* d_ws, size_t ws_size,
                              hipStream_t stream) {
  const float* z          = (const float*)d_in[0];
  const float* mask       = (const float*)d_in[1];
  const float* codebook   = (const float*)d_in[2];
  const float* ema_count  = (const float*)d_in[3];
  const float* ema_weight = (const float*)d_in[4];

  float* out        = (float*)d_out;
  float* out0       = out;                         // 4194304
  float* out_idx    = out + 4194304;               // 16384
  float* out_loss   = out + 4210688;               // 1
  float* out_count  = out + 4210689;               // 4096
  float* out_weight = out + 4214785;               // 1048576

  char* ws = (char*)d_ws;
  unsigned short* zpack = (unsigned short*)(ws + WS_ZPACK);
  unsigned short* cpack = (unsigned short*)(ws + WS_CPACK);
  double* cnorm    = (double*)(ws + WS_CNORM);
  double* cand_val = (double*)(ws + WS_CANDV);
  int*    cand_idx = (int*)   (ws + WS_CANDI);
  float*  dw       = (float*) (ws + WS_DW);
  float*  nacc     = (float*) (ws + WS_NACC);
  float*  loss2    = (float*) (ws + WS_LOSS);

  (void)hipMemsetAsync(ws + WS_DW, 0, WS_ZERO_BYTES, stream);

  vq_split_z<<<4096, 256, 0, stream>>>(z, zpack);
  vq_split_c<<<1024, 256, 0, stream>>>(codebook, cpack, cnorm);
  vq_gemm<<<4096, 256, 0, stream>>>(zpack, cpack, cnorm, cand_val, cand_idx);
  vq_merge_scatter<<<4096, 256, 0, stream>>>(cand_val, cand_idx, z, mask, codebook,
                                             out0, out_idx, dw, nacc, loss2);
  vq_finish_weight<<<1024, 256, 0, stream>>>(ema_weight, dw, out_weight);
  vq_finish_count<<<1, 256, 0, stream>>>(ema_count, nacc, loss2, out_count, out_loss);
}

// Round 2
// 299.404 us; speedup vs baseline: 2.0714x; 2.0714x over previous
//
#include <hip/hip_runtime.h>
#include <hip/hip_fp16.h>
#include <cstdint>
#include <cstddef>

// ---------------------------------------------------------------------------
// VectorQuantizerEMA on MI355X.
// Sizes fixed by the reference: B=8,S=2048,D=256,K=4096 -> N=16384 tokens.
// Pipeline:
//   1) split z and codebook into fp16 (h1, h2*2^11) packed rows [row][512 halves]
//      (+ fp64 codebook row norms)
//   2) distance GEMM via 3x mfma_f32_16x16x32_f16 (h1h1 -> acc1, cross -> acc2),
//      fp64 epilogue argmin per token per 128-entry block -> candidate arrays
//   3) merge candidates per token; gather codebook row -> out; per-token loss
//      array (NO same-address atomics); atomic scatter of n / dw (distributed)
//   4) new_weight elementwise; new_count normalize + deterministic loss reduce
// R1 change: loss2[0/1] same-address fp32 atomic chains (16384 serialized RMW
// each ~= 426us, the measured 429us) replaced by per-token stores + tree reduce.
// ---------------------------------------------------------------------------

#define N_TOK 16384
#define DIM   256
#define K_CB  4096

typedef _Float16 h8    __attribute__((ext_vector_type(8)));
typedef float    f32x4 __attribute__((ext_vector_type(4)));

// ---- ws layout (bytes) ----
#define WS_ZPACK   0u            // N_TOK * 512 halves  = 16 MB
#define WS_CPACK   16777216u     // K_CB * 512 halves   = 4 MB
#define WS_CNORM   20971520u     // K_CB doubles        = 32 KB
#define WS_CANDV   21004288u     // N_TOK * 64 doubles  = 8 MB
#define WS_CANDI   29392896u     // N_TOK * 64 int      = 4 MB
#define WS_DW      33587200u     // K_CB * DIM float    = 4 MB
#define WS_NACC    37781504u     // K_CB float          = 16 KB
#define WS_LTOK    37797888u     // N_TOK float         = 64 KB
#define WS_ZERO_BYTES (4194304u + 16384u)

__device__ __forceinline__ void gload_lds16(const void* g, void* l) {
  __builtin_amdgcn_global_load_lds(
      (const __attribute__((address_space(1))) uint32_t*)g,
      (__attribute__((address_space(3))) uint32_t*)l, 16, 0, 0);
}

// ---- 1a: split z into packed fp16 pair rows --------------------------------
__global__ void vq_split_z(const float* __restrict__ z, unsigned short* __restrict__ pack) {
  int tid = blockIdx.x * 256 + threadIdx.x;       // over N_TOK*64
  int row = tid >> 6, c4 = tid & 63;
  float4 v = reinterpret_cast<const float4*>(z)[tid];
  float x[4] = {v.x, v.y, v.z, v.w};
  union { _Float16 h[4]; ushort4 u; } a, b;
#pragma unroll
  for (int i = 0; i < 4; ++i) {
    _Float16 h1 = (_Float16)x[i];
    float lo = x[i] - (float)h1;
    a.h[i] = h1;
    b.h[i] = (_Float16)(lo * 2048.0f);   // scaled to avoid fp16 denormal loss
  }
  reinterpret_cast<ushort4*>(pack)[row * 128 + c4]      = a.u;
  reinterpret_cast<ushort4*>(pack)[row * 128 + 64 + c4] = b.u;
}

// ---- 1b: split codebook + fp64 row norms -----------------------------------
__global__ void vq_split_c(const float* __restrict__ cb, unsigned short* __restrict__ pack,
                           double* __restrict__ cnorm) {
  int w = threadIdx.x >> 6, l = threadIdx.x & 63;
  int row = blockIdx.x * 4 + w;
  float4 v = reinterpret_cast<const float4*>(cb)[row * 64 + l];
  float x[4] = {v.x, v.y, v.z, v.w};
  union { _Float16 h[4]; ushort4 u; } a, b;
  double ss = 0.0;
#pragma unroll
  for (int i = 0; i < 4; ++i) {
    _Float16 h1 = (_Float16)x[i];
    float lo = x[i] - (float)h1;
    a.h[i] = h1;
    b.h[i] = (_Float16)(lo * 2048.0f);
    ss += (double)x[i] * (double)x[i];
  }
  reinterpret_cast<ushort4*>(pack)[row * 128 + l]      = a.u;
  reinterpret_cast<ushort4*>(pack)[row * 128 + 64 + l] = b.u;
  for (int off = 1; off < 64; off <<= 1) ss += __shfl_xor(ss, off);
  if (l == 0) cnorm[row] = ss;
}

// ---- 2: distance GEMM + per-block argmin -----------------------------------
// Block: 256 thr = 4 waves (2x2). Tile 128 tokens x 128 entries, BK=32 halves.
// LDS row layout: [row][8 chunks of 16B], chunks 0-3 = h1 k0..31, 4-7 = h2s;
// stored chunk = logical_chunk ^ (row&7)  -> conflict-free ds_read_b128.
// global_load_lds writes linearly; the swizzle is applied on the global SOURCE.
__global__ __launch_bounds__(256, 2) void vq_gemm(
    const unsigned short* __restrict__ zpack, const unsigned short* __restrict__ cpack,
    const double* __restrict__ cnorm,
    double* __restrict__ cand_val, int* __restrict__ cand_idx) {
  __shared__ __align__(1024) unsigned char lds[32768];   // A 16KB | B 16KB

  // XCD-aware bijective swizzle: 4096 blocks, 8 XCDs, chunk of 512/XCD.
  // Within a chunk: 16 consecutive mb (fast) x 32 nb (slow) -> B-panel L2 reuse.
  const int bid = blockIdx.x;
  const int wg  = (bid & 7) * 512 + (bid >> 3);
  const int mb  = (wg >> 9) * 16 + (wg & 15);   // 0..127
  const int nb  = (wg >> 4) & 31;               // 0..31
  const int token0 = mb * 128, entry0 = nb * 128;

  const int tx = threadIdx.x;
  const int w  = tx >> 6, l = tx & 63;
  const int waveM = w >> 1, waveN = w & 1;

  // staging lane constants: each wave-load covers 8 rows x 8 chunks (1 KB)
  const int rlo = l >> 3;            // row within 8-row group
  const int ch  = l & 7;             // stored chunk this lane fills
  const int lc  = ch ^ rlo;          // logical chunk to fetch
  const int s_  = lc >> 2, c_ = lc & 3;
  const unsigned char* zb  = (const unsigned char*)zpack;
  const unsigned char* cbp = (const unsigned char*)cpack;
  const unsigned char* srcA[4]; const unsigned char* srcB[4];
  unsigned char* dstA[4]; unsigned char* dstB[4];
#pragma unroll
  for (int j = 0; j < 4; ++j) {
    size_t rA = (size_t)(token0 + w * 32 + j * 8 + rlo);
    size_t rB = (size_t)(entry0 + w * 32 + j * 8 + rlo);
    srcA[j] = zb  + rA * 1024 + s_ * 512 + c_ * 16;
    srcB[j] = cbp + rB * 1024 + s_ * 512 + c_ * 16;
    dstA[j] = &lds[0]     + (w * 32 + j * 8) * 128;
    dstB[j] = &lds[16384] + (w * 32 + j * 8) * 128;
  }

  f32x4 zero = {0.f, 0.f, 0.f, 0.f};
  f32x4 acc1[4][4], acc2[4][4];
#pragma unroll
  for (int m = 0; m < 4; ++m)
#pragma unroll
    for (int n = 0; n < 4; ++n) { acc1[m][n] = zero; acc2[m][n] = zero; }

  const int fr = l & 15, fk = l >> 4;

  for (int t = 0; t < 8; ++t) {
#pragma unroll
    for (int j = 0; j < 4; ++j) {
      gload_lds16(srcA[j] + t * 64, dstA[j]);
      gload_lds16(srcB[j] + t * 64, dstB[j]);
    }
    __syncthreads();

    h8 a1[4], a2[4], b1[4], b2[4];
#pragma unroll
    for (int m = 0; m < 4; ++m) {
      int r = waveM * 64 + m * 16 + fr;
      int st0 = (fk)     ^ (r & 7);
      int st1 = (4 + fk) ^ (r & 7);
      a1[m] = *(const h8*)&lds[r * 128 + st0 * 16];
      a2[m] = *(const h8*)&lds[r * 128 + st1 * 16];
    }
#pragma unroll
    for (int n = 0; n < 4; ++n) {
      int r = waveN * 64 + n * 16 + fr;
      int st0 = (fk)     ^ (r & 7);
      int st1 = (4 + fk) ^ (r & 7);
      b1[n] = *(const h8*)&lds[16384 + r * 128 + st0 * 16];
      b2[n] = *(const h8*)&lds[16384 + r * 128 + st1 * 16];
    }
#pragma unroll
    for (int m = 0; m < 4; ++m)
#pragma unroll
      for (int n = 0; n < 4; ++n) {
        acc1[m][n] = __builtin_amdgcn_mfma_f32_16x16x32_f16(a1[m], b1[n], acc1[m][n], 0, 0, 0);
        acc2[m][n] = __builtin_amdgcn_mfma_f32_16x16x32_f16(a1[m], b2[n], acc2[m][n], 0, 0, 0);
        acc2[m][n] = __builtin_amdgcn_mfma_f32_16x16x32_f16(a2[m], b1[n], acc2[m][n], 0, 0, 0);
      }
    __syncthreads();
  }

  // epilogue: d = |c|^2 - 2*(acc1 + acc2/2048) in fp64, per-token argmin
  double cn[4];
#pragma unroll
  for (int n = 0; n < 4; ++n) cn[n] = cnorm[entry0 + waveN * 64 + n * 16 + fr];

#pragma unroll
  for (int m = 0; m < 4; ++m) {
#pragma unroll
    for (int rI = 0; rI < 4; ++rI) {
      double bd = 1e300; int bi = 0x7fffffff;
#pragma unroll
      for (int n = 0; n < 4; ++n) {
        double s = (double)acc1[m][n][rI] + (double)acc2[m][n][rI] * (1.0 / 2048.0);
        double d = cn[n] - 2.0 * s;
        int e = entry0 + waveN * 64 + n * 16 + fr;
        if (d < bd || (d == bd && e < bi)) { bd = d; bi = e; }
      }
      for (int off = 1; off < 16; off <<= 1) {   // reduce across 16 fragment cols
        double od = __shfl_xor(bd, off);
        int    oi = __shfl_xor(bi, off);
        if (od < bd || (od == bd && oi < bi)) { bd = od; bi = oi; }
      }
      if (fr == 0) {
        int token = token0 + waveM * 64 + m * 16 + fk * 4 + rI;
        int slot  = nb * 2 + waveN;              // 64 slots per token
        cand_val[(size_t)token * 64 + slot] = bd;
        cand_idx[(size_t)token * 64 + slot] = bi;
      }
    }
  }
}

// ---- 3: merge candidates; out/indices/loss_tok; scatter n/dw ---------------
__global__ void vq_merge_scatter(
    const double* __restrict__ cand_val, const int* __restrict__ cand_idx,
    const float* __restrict__ z, const float* __restrict__ mask,
    const float* __restrict__ codebook,
    float* __restrict__ out0, float* __restrict__ out_idx,
    float* __restrict__ dw, float* __restrict__ nacc, float* __restrict__ loss_tok) {
  int w = threadIdx.x >> 6, l = threadIdx.x & 63;
  int token = blockIdx.x * 4 + w;

  double bv = cand_val[(size_t)token * 64 + l];
  int    bi = cand_idx[(size_t)token * 64 + l];
  for (int off = 1; off < 64; off <<= 1) {
    double ov = __shfl_xor(bv, off);
    int    oi = __shfl_xor(bi, off);
    if (ov < bv || (ov == bv && oi < bi)) { bv = ov; bi = oi; }
  }

  float4 cv = reinterpret_cast<const float4*>(codebook)[(size_t)bi * 64 + l];
  reinterpret_cast<float4*>(out0)[(size_t)token * 64 + l] = cv;   // out == quantized
  float4 zv = reinterpret_cast<const float4*>(z)[(size_t)token * 64 + l];

  float dx = zv.x - cv.x, dy = zv.y - cv.y, dz = zv.z - cv.z, dww = zv.w - cv.w;
  float ssd = dx * dx + dy * dy + dz * dz + dww * dww;
  for (int off = 1; off < 64; off <<= 1) ssd += __shfl_xor(ssd, off);

  float mk = mask[token];
  if (l == 0) {
    out_idx[token]  = (float)bi;
    loss_tok[token] = mk * ssd * (1.0f / 256.0f);   // no same-address atomics
    atomicAdd(&nacc[bi], mk);                       // 4 avg collisions/addr: fine
  }
  if (mk != 0.0f) {
    float* p = dw + (size_t)bi * 256 + l * 4;
    atomicAdd(p + 0, mk * zv.x);
    atomicAdd(p + 1, mk * zv.y);
    atomicAdd(p + 2, mk * zv.z);
    atomicAdd(p + 3, mk * zv.w);
  }
}

// ---- 4a: new_weight --------------------------------------------------------
__global__ void vq_finish_weight(const float* __restrict__ ew, const float* __restrict__ dw,
                                 float* __restrict__ nw) {
  int i = blockIdx.x * 256 + threadIdx.x;       // over K*D/4
  float4 e = reinterpret_cast<const float4*>(ew)[i];
  float4 d = reinterpret_cast<const float4*>(dw)[i];
  float4 o;
  o.x = 0.99f * e.x + 0.01f * d.x;
  o.y = 0.99f * e.y + 0.01f * d.y;
  o.z = 0.99f * e.z + 0.01f * d.z;
  o.w = 0.99f * e.w + 0.01f * d.w;
  reinterpret_cast<float4*>(nw)[i] = o;
}

// ---- 4b: new_count normalize + deterministic loss reduce -------------------
__global__ void vq_finish_count(const float* __restrict__ ec, const float* __restrict__ nacc,
                                const float* __restrict__ loss_tok, const float* __restrict__ mask,
                                float* __restrict__ out_count, float* __restrict__ out_loss) {
  __shared__ float nc_s[K_CB];
  __shared__ float red[256];
  int tid = threadIdx.x;
  float part = 0.f;
  for (int i = tid; i < K_CB; i += 256) {
    float nc = 0.99f * ec[i] + 0.01f * nacc[i];
    nc_s[i] = nc; part += nc;
  }
  red[tid] = part; __syncthreads();
  for (int s = 128; s > 0; s >>= 1) { if (tid < s) red[tid] += red[tid + s]; __syncthreads(); }
  float total = red[0];
  float scale = total / (total + (float)K_CB * 1e-5f);
  for (int i = tid; i < K_CB; i += 256) out_count[i] = (nc_s[i] + 1e-5f) * scale;
  __syncthreads();

  float ln = 0.f, lm = 0.f;
  for (int i = tid; i < N_TOK; i += 256) { ln += loss_tok[i]; lm += mask[i]; }
  red[tid] = ln; __syncthreads();
  for (int s = 128; s > 0; s >>= 1) { if (tid < s) red[tid] += red[tid + s]; __syncthreads(); }
  ln = red[0]; __syncthreads();
  red[tid] = lm; __syncthreads();
  for (int s = 128; s > 0; s >>= 1) { if (tid < s) red[tid] += red[tid + s]; __syncthreads(); }
  lm = red[0];
  if (tid == 0) out_loss[0] = 2.5f * ln / lm;   // 10 * 0.25 * num/den
}

extern "C" void kernel_launch(void* const* d_in, const int* in_sizes, int n_in,
                              void* d_out, int out_size, void* d_ws, size_t ws_size,
                              hipStream_t stream) {
  const float* z          = (const float*)d_in[0];
  const float* mask       = (const float*)d_in[1];
  const float* codebook   = (const float*)d_in[2];
  const float* ema_count  = (const float*)d_in[3];
  const float* ema_weight = (const float*)d_in[4];

  float* out        = (float*)d_out;
  float* out0       = out;                         // 4194304
  float* out_idx    = out + 4194304;               // 16384
  float* out_loss   = out + 4210688;               // 1
  float* out_count  = out + 4210689;               // 4096
  float* out_weight = out + 4214785;               // 1048576

  char* ws = (char*)d_ws;
  unsigned short* zpack = (unsigned short*)(ws + WS_ZPACK);
  unsigned short* cpack = (unsigned short*)(ws + WS_CPACK);
  double* cnorm    = (double*)(ws + WS_CNORM);
  double* cand_val = (double*)(ws + WS_CANDV);
  int*    cand_idx = (int*)   (ws + WS_CANDI);
  float*  dw       = (float*) (ws + WS_DW);
  float*  nacc     = (float*) (ws + WS_NACC);
  float*  loss_tok = (float*) (ws + WS_LTOK);

  (void)hipMemsetAsync(ws + WS_DW, 0, WS_ZERO_BYTES, stream);

  vq_split_z<<<4096, 256, 0, stream>>>(z, zpack);
  vq_split_c<<<1024, 256, 0, stream>>>(codebook, cpack, cnorm);
  vq_gemm<<<4096, 256, 0, stream>>>(zpack, cpack, cnorm, cand_val, cand_idx);
  vq_merge_scatter<<<4096, 256, 0, stream>>>(cand_val, cand_idx, z, mask, codebook,
                                             out0, out_idx, dw, nacc, loss_tok);
  vq_finish_weight<<<1024, 256, 0, stream>>>(ema_weight, dw, out_weight);
  vq_finish_count<<<1, 256, 0, stream>>>(ema_count, nacc, loss_tok, mask,
                                         out_count, out_loss);
}

// Round 3
// 275.483 us; speedup vs baseline: 2.2513x; 1.0868x over previous
//
#include <hip/hip_runtime.h>
#include <hip/hip_fp16.h>
#include <cstdint>
#include <cstddef>

// ---------------------------------------------------------------------------
// VectorQuantizerEMA on MI355X.  B=8,S=2048,D=256,K=4096 -> N=16384 tokens.
//   1) split z / codebook into fp16 (h1, h2*2^11) packed rows (+ fp64 norms)
//   2) distance GEMM: 3x mfma_f32_16x16x32_f16 per frag (h1h1 -> acc1,
//      cross terms -> acc2), fp64 epilogue argmin -> 64 candidates/token
//   3) merge candidates; gather codebook row -> out; block loss partials;
//      distributed atomic scatter of n / dw
//   4) new_weight elementwise; new_count normalize + loss finalize
// R1: removed same-address atomic chains (429us -> gone).
// R2: vq_gemm 2-phase double-buffered pipeline (stage t+1 before compute t,
//     ONE barrier/iter at end) per T3 minimum recipe; merge writes per-block
//     loss/mask partials so finish_count reads 32KB not 128KB.
// ---------------------------------------------------------------------------

#define N_TOK 16384
#define DIM   256
#define K_CB  4096

typedef _Float16 h8    __attribute__((ext_vector_type(8)));
typedef float    f32x4 __attribute__((ext_vector_type(4)));

// ---- ws layout (bytes) ----
#define WS_ZPACK   0u            // N_TOK * 512 halves  = 16 MB
#define WS_CPACK   16777216u     // K_CB * 512 halves   = 4 MB
#define WS_CNORM   20971520u     // K_CB doubles        = 32 KB
#define WS_CANDV   21004288u     // N_TOK * 64 doubles  = 8 MB
#define WS_CANDI   29392896u     // N_TOK * 64 int      = 4 MB
#define WS_DW      33587200u     // K_CB * DIM float    = 4 MB
#define WS_NACC    37781504u     // K_CB float          = 16 KB
#define WS_LPART   37797888u     // 4096 float block loss partials
#define WS_MPART   37814272u     // 4096 float block mask partials
#define WS_ZERO_BYTES (4194304u + 16384u)

__device__ __forceinline__ void gload_lds16(const void* g, void* l) {
  __builtin_amdgcn_global_load_lds(
      (const __attribute__((address_space(1))) uint32_t*)g,
      (__attribute__((address_space(3))) uint32_t*)l, 16, 0, 0);
}

// ---- 1a: split z into packed fp16 pair rows --------------------------------
__global__ void vq_split_z(const float* __restrict__ z, unsigned short* __restrict__ pack) {
  int tid = blockIdx.x * 256 + threadIdx.x;       // over N_TOK*64
  int row = tid >> 6, c4 = tid & 63;
  float4 v = reinterpret_cast<const float4*>(z)[tid];
  float x[4] = {v.x, v.y, v.z, v.w};
  union { _Float16 h[4]; ushort4 u; } a, b;
#pragma unroll
  for (int i = 0; i < 4; ++i) {
    _Float16 h1 = (_Float16)x[i];
    float lo = x[i] - (float)h1;
    a.h[i] = h1;
    b.h[i] = (_Float16)(lo * 2048.0f);   // scaled to avoid fp16 denormal loss
  }
  reinterpret_cast<ushort4*>(pack)[row * 128 + c4]      = a.u;
  reinterpret_cast<ushort4*>(pack)[row * 128 + 64 + c4] = b.u;
}

// ---- 1b: split codebook + fp64 row norms -----------------------------------
__global__ void vq_split_c(const float* __restrict__ cb, unsigned short* __restrict__ pack,
                           double* __restrict__ cnorm) {
  int w = threadIdx.x >> 6, l = threadIdx.x & 63;
  int row = blockIdx.x * 4 + w;
  float4 v = reinterpret_cast<const float4*>(cb)[row * 64 + l];
  float x[4] = {v.x, v.y, v.z, v.w};
  union { _Float16 h[4]; ushort4 u; } a, b;
  double ss = 0.0;
#pragma unroll
  for (int i = 0; i < 4; ++i) {
    _Float16 h1 = (_Float16)x[i];
    float lo = x[i] - (float)h1;
    a.h[i] = h1;
    b.h[i] = (_Float16)(lo * 2048.0f);
    ss += (double)x[i] * (double)x[i];
  }
  reinterpret_cast<ushort4*>(pack)[row * 128 + l]      = a.u;
  reinterpret_cast<ushort4*>(pack)[row * 128 + 64 + l] = b.u;
  for (int off = 1; off < 64; off <<= 1) ss += __shfl_xor(ss, off);
  if (l == 0) cnorm[row] = ss;
}

// ---- 2: distance GEMM + per-block argmin -----------------------------------
// 4 waves (2x2), tile 128 tokens x 128 entries, BK=32 halves, double-buffered.
// LDS row: [row][8 chunks of 16B], chunks 0-3 = h1, 4-7 = h2; stored chunk =
// logical ^ (row&7) -> conflict-free ds_read_b128 (swizzle applied on the
// global SOURCE address; global_load_lds writes linearly).
// 2-phase pipeline: STAGE(t+1, other buf); ds_read+MFMA(t); barrier.
__global__ __launch_bounds__(256, 2) void vq_gemm(
    const unsigned short* __restrict__ zpack, const unsigned short* __restrict__ cpack,
    const double* __restrict__ cnorm,
    double* __restrict__ cand_val, int* __restrict__ cand_idx) {
  __shared__ __align__(1024) unsigned char lds[65536];   // 2 x (A 16KB | B 16KB)

  // XCD-aware bijective swizzle: 4096 blocks, 8 XCDs, chunk of 512/XCD.
  const int bid = blockIdx.x;
  const int wg  = (bid & 7) * 512 + (bid >> 3);
  const int mb  = (wg >> 9) * 16 + (wg & 15);   // 0..127
  const int nb  = (wg >> 4) & 31;               // 0..31
  const int token0 = mb * 128, entry0 = nb * 128;

  const int tx = threadIdx.x;
  const int w  = tx >> 6, l = tx & 63;
  const int waveM = w >> 1, waveN = w & 1;

  // staging lane constants: each wave-load covers 8 rows x 8 chunks (1 KB)
  const int rlo = l >> 3;            // row within 8-row group
  const int ch  = l & 7;             // stored chunk this lane fills
  const int lc  = ch ^ rlo;          // logical chunk to fetch
  const int s_  = lc >> 2, c_ = lc & 3;
  const unsigned char* zb  = (const unsigned char*)zpack;
  const unsigned char* cbp = (const unsigned char*)cpack;
  const unsigned char* srcA[4]; const unsigned char* srcB[4];
  unsigned dA[4], dB[4];
#pragma unroll
  for (int j = 0; j < 4; ++j) {
    size_t rA = (size_t)(token0 + w * 32 + j * 8 + rlo);
    size_t rB = (size_t)(entry0 + w * 32 + j * 8 + rlo);
    srcA[j] = zb  + rA * 1024 + s_ * 512 + c_ * 16;
    srcB[j] = cbp + rB * 1024 + s_ * 512 + c_ * 16;
    dA[j] = (unsigned)((w * 32 + j * 8) * 128);
    dB[j] = 16384u + (unsigned)((w * 32 + j * 8) * 128);
  }

  f32x4 zero = {0.f, 0.f, 0.f, 0.f};
  f32x4 acc1[4][4], acc2[4][4];
#pragma unroll
  for (int m = 0; m < 4; ++m)
#pragma unroll
    for (int n = 0; n < 4; ++n) { acc1[m][n] = zero; acc2[m][n] = zero; }

  const int fr = l & 15, fk = l >> 4;

  // prologue: stage tile 0 into buffer 0
#pragma unroll
  for (int j = 0; j < 4; ++j) {
    gload_lds16(srcA[j], &lds[dA[j]]);
    gload_lds16(srcB[j], &lds[dB[j]]);
  }
  __syncthreads();   // vmcnt(0) drain + barrier (prologue only)

  unsigned cur = 0;
  for (int t = 0; t < 8; ++t) {
    if (t < 7) {                      // stage t+1 into other buffer FIRST
      unsigned off = (cur ^ 1) * 32768u;
#pragma unroll
      for (int j = 0; j < 4; ++j) {
        gload_lds16(srcA[j] + (t + 1) * 64, &lds[off + dA[j]]);
        gload_lds16(srcB[j] + (t + 1) * 64, &lds[off + dB[j]]);
      }
    }

    const unsigned char* la = &lds[cur * 32768u];
    const unsigned char* lb = la + 16384;
    h8 a1[4], a2[4], b1[4], b2[4];
#pragma unroll
    for (int m = 0; m < 4; ++m) {
      int r = waveM * 64 + m * 16 + fr;
      int st0 = (fk)     ^ (r & 7);
      int st1 = (4 + fk) ^ (r & 7);
      a1[m] = *(const h8*)&la[r * 128 + st0 * 16];
      a2[m] = *(const h8*)&la[r * 128 + st1 * 16];
    }
#pragma unroll
    for (int n = 0; n < 4; ++n) {
      int r = waveN * 64 + n * 16 + fr;
      int st0 = (fk)     ^ (r & 7);
      int st1 = (4 + fk) ^ (r & 7);
      b1[n] = *(const h8*)&lb[r * 128 + st0 * 16];
      b2[n] = *(const h8*)&lb[r * 128 + st1 * 16];
    }

    __builtin_amdgcn_s_setprio(1);
#pragma unroll
    for (int m = 0; m < 4; ++m)
#pragma unroll
      for (int n = 0; n < 4; ++n) {
        acc1[m][n] = __builtin_amdgcn_mfma_f32_16x16x32_f16(a1[m], b1[n], acc1[m][n], 0, 0, 0);
        acc2[m][n] = __builtin_amdgcn_mfma_f32_16x16x32_f16(a1[m], b2[n], acc2[m][n], 0, 0, 0);
        acc2[m][n] = __builtin_amdgcn_mfma_f32_16x16x32_f16(a2[m], b1[n], acc2[m][n], 0, 0, 0);
      }
    __builtin_amdgcn_s_setprio(0);

    if (t < 7) {
      __syncthreads();   // vmcnt(0): prefetch has had whole MFMA phase to land
      cur ^= 1;
    }
  }

  // epilogue: d = |c|^2 - 2*(acc1 + acc2/2048) in fp64, per-token argmin
  double cn[4];
#pragma unroll
  for (int n = 0; n < 4; ++n) cn[n] = cnorm[entry0 + waveN * 64 + n * 16 + fr];

#pragma unroll
  for (int m = 0; m < 4; ++m) {
#pragma unroll
    for (int rI = 0; rI < 4; ++rI) {
      double bd = 1e300; int bi = 0x7fffffff;
#pragma unroll
      for (int n = 0; n < 4; ++n) {
        double s = (double)acc1[m][n][rI] + (double)acc2[m][n][rI] * (1.0 / 2048.0);
        double d = cn[n] - 2.0 * s;
        int e = entry0 + waveN * 64 + n * 16 + fr;
        if (d < bd || (d == bd && e < bi)) { bd = d; bi = e; }
      }
      for (int off = 1; off < 16; off <<= 1) {   // reduce across 16 fragment cols
        double od = __shfl_xor(bd, off);
        int    oi = __shfl_xor(bi, off);
        if (od < bd || (od == bd && oi < bi)) { bd = od; bi = oi; }
      }
      if (fr == 0) {
        int token = token0 + waveM * 64 + m * 16 + fk * 4 + rI;
        int slot  = nb * 2 + waveN;              // 64 slots per token
        cand_val[(size_t)token * 64 + slot] = bd;
        cand_idx[(size_t)token * 64 + slot] = bi;
      }
    }
  }
}

// ---- 3: merge candidates; out/indices; block loss partials; scatter n/dw ---
__global__ void vq_merge_scatter(
    const double* __restrict__ cand_val, const int* __restrict__ cand_idx,
    const float* __restrict__ z, const float* __restrict__ mask,
    const float* __restrict__ codebook,
    float* __restrict__ out0, float* __restrict__ out_idx,
    float* __restrict__ dw, float* __restrict__ nacc,
    float* __restrict__ loss_part, float* __restrict__ mask_part) {
  __shared__ float ls[4], ms[4];
  int w = threadIdx.x >> 6, l = threadIdx.x & 63;
  int token = blockIdx.x * 4 + w;

  double bv = cand_val[(size_t)token * 64 + l];
  int    bi = cand_idx[(size_t)token * 64 + l];
  for (int off = 1; off < 64; off <<= 1) {
    double ov = __shfl_xor(bv, off);
    int    oi = __shfl_xor(bi, off);
    if (ov < bv || (ov == bv && oi < bi)) { bv = ov; bi = oi; }
  }

  float4 cv = reinterpret_cast<const float4*>(codebook)[(size_t)bi * 64 + l];
  reinterpret_cast<float4*>(out0)[(size_t)token * 64 + l] = cv;   // out == quantized
  float4 zv = reinterpret_cast<const float4*>(z)[(size_t)token * 64 + l];

  float dx = zv.x - cv.x, dy = zv.y - cv.y, dz = zv.z - cv.z, dww = zv.w - cv.w;
  float ssd = dx * dx + dy * dy + dz * dz + dww * dww;
  for (int off = 1; off < 64; off <<= 1) ssd += __shfl_xor(ssd, off);

  float mk = mask[token];
  if (l == 0) {
    out_idx[token] = (float)bi;
    ls[w] = mk * ssd * (1.0f / 256.0f);
    ms[w] = mk;
    atomicAdd(&nacc[bi], mk);          // ~4 avg collisions/addr: pipelines fine
  }
  if (mk != 0.0f) {
    float* p = dw + (size_t)bi * 256 + l * 4;
    atomicAdd(p + 0, mk * zv.x);
    atomicAdd(p + 1, mk * zv.y);
    atomicAdd(p + 2, mk * zv.z);
    atomicAdd(p + 3, mk * zv.w);
  }
  __syncthreads();
  if (threadIdx.x == 0) {
    loss_part[blockIdx.x] = ls[0] + ls[1] + ls[2] + ls[3];
    mask_part[blockIdx.x] = ms[0] + ms[1] + ms[2] + ms[3];
  }
}

// ---- 4a: new_weight --------------------------------------------------------
__global__ void vq_finish_weight(const float* __restrict__ ew, const float* __restrict__ dw,
                                 float* __restrict__ nw) {
  int i = blockIdx.x * 256 + threadIdx.x;       // over K*D/4
  float4 e = reinterpret_cast<const float4*>(ew)[i];
  float4 d = reinterpret_cast<const float4*>(dw)[i];
  float4 o;
  o.x = 0.99f * e.x + 0.01f * d.x;
  o.y = 0.99f * e.y + 0.01f * d.y;
  o.z = 0.99f * e.z + 0.01f * d.z;
  o.w = 0.99f * e.w + 0.01f * d.w;
  reinterpret_cast<float4*>(nw)[i] = o;
}

// ---- 4b: new_count normalize + deterministic loss reduce -------------------
__global__ void vq_finish_count(const float* __restrict__ ec, const float* __restrict__ nacc,
                                const float* __restrict__ loss_part,
                                const float* __restrict__ mask_part,
                                float* __restrict__ out_count, float* __restrict__ out_loss) {
  __shared__ float nc_s[K_CB];
  __shared__ float red[256];
  int tid = threadIdx.x;
  float part = 0.f;
  for (int i = tid; i < K_CB; i += 256) {
    float nc = 0.99f * ec[i] + 0.01f * nacc[i];
    nc_s[i] = nc; part += nc;
  }
  red[tid] = part; __syncthreads();
  for (int s = 128; s > 0; s >>= 1) { if (tid < s) red[tid] += red[tid + s]; __syncthreads(); }
  float total = red[0];
  float scale = total / (total + (float)K_CB * 1e-5f);
  for (int i = tid; i < K_CB; i += 256) out_count[i] = (nc_s[i] + 1e-5f) * scale;
  __syncthreads();

  float ln = 0.f, lm = 0.f;
  for (int i = tid; i < 4096; i += 256) { ln += loss_part[i]; lm += mask_part[i]; }
  red[tid] = ln; __syncthreads();
  for (int s = 128; s > 0; s >>= 1) { if (tid < s) red[tid] += red[tid + s]; __syncthreads(); }
  ln = red[0]; __syncthreads();
  red[tid] = lm; __syncthreads();
  for (int s = 128; s > 0; s >>= 1) { if (tid < s) red[tid] += red[tid + s]; __syncthreads(); }
  lm = red[0];
  if (tid == 0) out_loss[0] = 2.5f * ln / lm;   // 10 * 0.25 * num/den
}

extern "C" void kernel_launch(void* const* d_in, const int* in_sizes, int n_in,
                              void* d_out, int out_size, void* d_ws, size_t ws_size,
                              hipStream_t stream) {
  const float* z          = (const float*)d_in[0];
  const float* mask       = (const float*)d_in[1];
  const float* codebook   = (const float*)d_in[2];
  const float* ema_count  = (const float*)d_in[3];
  const float* ema_weight = (const float*)d_in[4];

  float* out        = (float*)d_out;
  float* out0       = out;                         // 4194304
  float* out_idx    = out + 4194304;               // 16384
  float* out_loss   = out + 4210688;               // 1
  float* out_count  = out + 4210689;               // 4096
  float* out_weight = out + 4214785;               // 1048576

  char* ws = (char*)d_ws;
  unsigned short* zpack = (unsigned short*)(ws + WS_ZPACK);
  unsigned short* cpack = (unsigned short*)(ws + WS_CPACK);
  double* cnorm    = (double*)(ws + WS_CNORM);
  double* cand_val = (double*)(ws + WS_CANDV);
  int*    cand_idx = (int*)   (ws + WS_CANDI);
  float*  dw       = (float*) (ws + WS_DW);
  float*  nacc     = (float*) (ws + WS_NACC);
  float*  lpart    = (float*) (ws + WS_LPART);
  float*  mpart    = (float*) (ws + WS_MPART);

  (void)hipMemsetAsync(ws + WS_DW, 0, WS_ZERO_BYTES, stream);

  vq_split_z<<<4096, 256, 0, stream>>>(z, zpack);
  vq_split_c<<<1024, 256, 0, stream>>>(codebook, cpack, cnorm);
  vq_gemm<<<4096, 256, 0, stream>>>(zpack, cpack, cnorm, cand_val, cand_idx);
  vq_merge_scatter<<<4096, 256, 0, stream>>>(cand_val, cand_idx, z, mask, codebook,
                                             out0, out_idx, dw, nacc, lpart, mpart);
  vq_finish_weight<<<1024, 256, 0, stream>>>(ema_weight, dw, out_weight);
  vq_finish_count<<<1, 256, 0, stream>>>(ema_count, nacc, lpart, mpart,
                                         out_count, out_loss);
}